// Round 2
// 461.847 us; speedup vs baseline: 1.0084x; 1.0084x over previous
//
#include <hip/hip_runtime.h>

// DeepSeek MoE (N=2048, D=768, I=3072, E=8, K=2 + shared expert), fp32 in/out,
// bf16 MFMA compute. R5 (resubmit; previous run died to container-acquire
// flake, no counters): w2/w2s transpose moved OUT of prep_kernel and folded
// into the gemm_act launch as interleaved blocks (1 gemm row : 2 transpose
// rows) -- the memory-bound transpose overlaps the compute-bound GEMM1, which
// has idle HBM bandwidth. gemm_out (sole consumer of w2b) launches after
// gemm_act, so ordering is preserved. Otherwise identical to R4: XOR-swizzled
// LDS GEMM tiles, fused gather, BK=64, split-K=2 out-GEMM with fp32 partials.

#define D_ 768
#define I_ 3072
#define E_ 8
#define NTOK 2048
#define NPMAX 5120          // 4096 pairs + worst-case 128-padding per expert
#define MAXTILES 40
#define NSHT 16             // shared-expert M tiles: 2048/128
#define ROWS (NTOK + NPMAX) // unified act/out rows
#define SPLITK 2
#define KS_ (I_ / SPLITK)   // 1536

#define NT2 5184            // w2/w2s transpose blocks (9 * 576)

typedef __bf16 bf16x8 __attribute__((ext_vector_type(8)));
typedef float floatx4 __attribute__((ext_vector_type(4)));

#define GLOAD_LDS16(g, l) __builtin_amdgcn_global_load_lds( \
    (const __attribute__((address_space(1))) void*)(g),     \
    (__attribute__((address_space(3))) void*)(l), 16, 0, 0)

__device__ __forceinline__ unsigned short f2b(float f) {
    unsigned int u = __float_as_uint(f);
    u += 0x7fffu + ((u >> 16) & 1u);          // RNE to bf16
    return (unsigned short)(u >> 16);
}

// ---------------- prep: w1/w3 transposes + cast_x + gating ------------------

__global__ __launch_bounds__(256) void prep_kernel(
    const float* __restrict__ x, const float* __restrict__ gw,
    const float* __restrict__ gbias,
    const float* __restrict__ w1, const float* __restrict__ w3,
    const float* __restrict__ w1s, const float* __restrict__ w3s,
    unsigned short* __restrict__ xb,
    unsigned short* __restrict__ w1b, unsigned short* __restrict__ w3b,
    unsigned short* __restrict__ w1sb, unsigned short* __restrict__ w3sb,
    int* __restrict__ idx, float* __restrict__ wts) {
    __shared__ float t[64][65];
    int b = blockIdx.x, tid = threadIdx.x;
    if (b < 10368) {
        const float* s; unsigned short* d;
        int z = b / 576, r = b % 576;
        int bx = r % 48, by = r / 48;
        const int R = D_, C = I_;
        if (z < 8)       { s = w1 + (size_t)z * D_ * I_;       d = w1b + (size_t)z * D_ * I_; }
        else if (z < 16) { s = w3 + (size_t)(z - 8) * D_ * I_; d = w3b + (size_t)(z - 8) * D_ * I_; }
        else if (z == 16){ s = w1s; d = w1sb; }
        else             { s = w3s; d = w3sb; }
        int c0 = bx * 64, r0 = by * 64;
#pragma unroll
        for (int j = 0; j < 4; j++) {
            int slot = tid + j * 256;
            int rr = slot >> 4, c4 = (slot & 15) * 4;
            float4 v = *(const float4*)(s + (size_t)(r0 + rr) * C + c0 + c4);
            t[rr][c4] = v.x; t[rr][c4 + 1] = v.y; t[rr][c4 + 2] = v.z; t[rr][c4 + 3] = v.w;
        }
        __syncthreads();
#pragma unroll
        for (int j = 0; j < 2; j++) {
            int slot = tid + j * 256;
            int c = slot >> 3, rs = (slot & 7) * 8;
            unsigned short o[8] __attribute__((aligned(16)));
#pragma unroll
            for (int i = 0; i < 8; i++) o[i] = f2b(t[rs + i][c]);
            *(int4*)(d + (size_t)(c0 + c) * R + r0 + rs) = *(const int4*)o;
        }
    } else if (b < 11904) {
        int gid = (b - 10368) * 256 + tid;
        float4 v = *(const float4*)(x + (size_t)gid * 4);
        ushort4 o;
        o.x = f2b(v.x); o.y = f2b(v.y); o.z = f2b(v.z); o.w = f2b(v.w);
        *(ushort4*)(xb + (size_t)gid * 4) = o;
    } else {
        int tok = (b - 11904) * 4 + (tid >> 6);
        int lane = tid & 63;
        float z[E_];
#pragma unroll
        for (int e = 0; e < E_; e++) z[e] = 0.f;
        const float* xr = x + (size_t)tok * D_;
        for (int j = lane; j < D_; j += 64) {
            float xv = xr[j];
            const float* g = gw + (size_t)j * E_;
#pragma unroll
            for (int e = 0; e < E_; e++) z[e] += xv * g[e];
        }
#pragma unroll
        for (int off = 32; off > 0; off >>= 1)
#pragma unroll
            for (int e = 0; e < E_; e++) z[e] += __shfl_down(z[e], off, 64);
        if (lane == 0) {
            float s[E_], r[E_];
#pragma unroll
            for (int e = 0; e < E_; e++) {
                float zz = z[e];
                float sp = zz > 0.f ? zz + log1pf(expf(-zz)) : log1pf(expf(zz));
                s[e] = sqrtf(sp);
                r[e] = s[e] + gbias[e];
            }
            int i0 = 0;
            for (int e = 1; e < E_; e++) if (r[e] > r[i0]) i0 = e;
            int i1 = (i0 == 0) ? 1 : 0;
            for (int e = 0; e < E_; e++) if (e != i0 && r[e] > r[i1]) i1 = e;
            float w0 = s[i0], w1v = s[i1];
            float inv = 1.f / fmaxf(w0 + w1v, 1e-6f);
            idx[2 * tok] = i0; idx[2 * tok + 1] = i1;
            wts[2 * tok] = w0 * inv; wts[2 * tok + 1] = w1v * inv;
        }
    }
}

// ---------------- routing build (single block) ----------------

__global__ void route_build_kernel(const int* __restrict__ idx,
                                   const float* __restrict__ wts,
                                   int* __restrict__ pair_token,
                                   float* __restrict__ pair_w,
                                   int* __restrict__ pos_of,
                                   int* __restrict__ tiles) {
    __shared__ int cnt[E_], seg[E_], cur[E_];
    int tid = threadIdx.x;
    if (tid < E_) { cnt[tid] = 0; cur[tid] = 0; }
    __syncthreads();
    for (int p = tid; p < NTOK * 2; p += 256) atomicAdd(&cnt[idx[p]], 1);
    __syncthreads();
    if (tid == 0) {
        int off = 0, nt = 0;
        for (int e = 0; e < E_; e++) {
            seg[e] = off;
            int te = (cnt[e] + 127) >> 7;
            for (int j = 0; j < te; j++) {
                tiles[nt * 2] = e; tiles[nt * 2 + 1] = off + j * 128; nt++;
            }
            off += te * 128;
        }
        for (; nt < MAXTILES; nt++) { tiles[nt * 2] = -1; tiles[nt * 2 + 1] = 0; }
    }
    for (int p = tid; p < NPMAX; p += 256) pair_token[p] = -1;
    __syncthreads();
    for (int p = tid; p < NTOK * 2; p += 256) {
        int e = idx[p];
        int r = atomicAdd(&cur[e], 1);
        int pos = seg[e] + r;
        pair_token[pos] = p >> 1;
        pair_w[pos] = wts[p];
        pos_of[p] = pos;
    }
}

// ---------------- GEMM 1: fused gate/up + activation + w2 transpose --------
// blockIdx.y % 3 == 0 -> GEMM row (56 rows); else -> w2/w2s transpose block.
// GEMM: BM=128, BN=64 per weight, BK=64, XOR-swizzled LDS, fused gather.
// Transpose blocks reuse the GEMM LDS as a 64x65 fp32 scratch; they overlap
// the MFMA-bound GEMM using its idle HBM bandwidth. gemm_out (the only
// consumer of w2b/w2sb) launches after this kernel completes.

__launch_bounds__(256)
__global__ void gemm_act_kernel(const unsigned short* __restrict__ xb,
                                const unsigned short* __restrict__ w1sb,
                                const unsigned short* __restrict__ w3sb,
                                const unsigned short* __restrict__ w1b,
                                const unsigned short* __restrict__ w3b,
                                const int* __restrict__ tiles,
                                const int* __restrict__ pair_token,
                                unsigned short* __restrict__ act,
                                const float* __restrict__ w2,
                                const float* __restrict__ w2s,
                                unsigned short* __restrict__ w2b,
                                unsigned short* __restrict__ w2sb) {
    __shared__ __align__(16) unsigned short smem[128 * 64 + 64 * 64 + 64 * 64]; // 32 KB
    unsigned short* As  = smem;
    unsigned short* Bs1 = smem + 128 * 64;
    unsigned short* Bs3 = smem + 128 * 64 + 64 * 64;

    int bxi = blockIdx.x, byi = blockIdx.y;
    int tid = threadIdx.x;

    if (byi % 3) {
        // ---- w2 / w2s transpose block ----
        int slot = byi - byi / 3 - 1;          // 0..111
        int b2 = slot * 48 + bxi;              // 0..5375
        if (b2 >= NT2) return;
        float (*t)[65] = (float(*)[65])smem;   // 64*65*4 = 16640 B < 32 KB
        const float* s; unsigned short* dst;
        int z = b2 / 576, r = b2 % 576;
        int tx = r % 12, ty = r / 12;
        const int R = I_, C = D_;
        if (z < 8) { s = w2 + (size_t)z * I_ * D_; dst = w2b + (size_t)z * I_ * D_; }
        else       { s = w2s; dst = w2sb; }
        int c0 = tx * 64, r0 = ty * 64;
#pragma unroll
        for (int j = 0; j < 4; j++) {
            int sl = tid + j * 256;
            int rr = sl >> 4, c4 = (sl & 15) * 4;
            float4 v = *(const float4*)(s + (size_t)(r0 + rr) * C + c0 + c4);
            t[rr][c4] = v.x; t[rr][c4 + 1] = v.y; t[rr][c4 + 2] = v.z; t[rr][c4 + 3] = v.w;
        }
        __syncthreads();
#pragma unroll
        for (int j = 0; j < 2; j++) {
            int sl = tid + j * 256;
            int c = sl >> 3, rs = (sl & 7) * 8;
            unsigned short o[8] __attribute__((aligned(16)));
#pragma unroll
            for (int i = 0; i < 8; i++) o[i] = f2b(t[rs + i][c]);
            *(int4*)(dst + (size_t)(c0 + c) * R + r0 + rs) = *(const int4*)o;
        }
        return;
    }

    int mt = byi / 3;                          // 0..55
    const unsigned short *B1, *B3;
    int m0; bool routed;
    if (mt < NSHT) {
        B1 = w1sb; B3 = w3sb; m0 = mt * 128; routed = false;
    } else {
        int e = tiles[(mt - NSHT) * 2];
        if (e < 0) return;
        m0 = NTOK + tiles[(mt - NSHT) * 2 + 1];
        B1 = w1b + (size_t)e * I_ * D_; B3 = w3b + (size_t)e * I_ * D_;
        routed = true;
    }
    int n0 = bxi * 64;
    int lane = tid & 63, wave = tid >> 6;
    int wm = (wave & 1) * 64, wn = (wave >> 1) * 32;
    int l15 = lane & 15, quad = lane >> 4;

    // staging: per inst a wave covers 8 rows x 8 granules (16B each).
    int rl = lane >> 3;                 // row within 8-row group
    int ph = lane & 7;                  // physical granule (LDS position)
    int lg = ph ^ rl;                   // logical granule (row&7 == rl)
    const unsigned short* asrc[4];
#pragma unroll
    for (int j = 0; j < 4; j++) {
        int r = j * 32 + wave * 8 + rl;
        int tok;
        if (routed) { tok = pair_token[m0 - NTOK + r]; if (tok < 0) tok = 0; }
        else tok = m0 + r;
        asrc[j] = xb + (size_t)tok * D_ + lg * 8;
    }
    const unsigned short *b1src[2], *b3src[2];
#pragma unroll
    for (int j = 0; j < 2; j++) {
        int r = j * 32 + wave * 8 + rl;
        b1src[j] = B1 + (size_t)(n0 + r) * D_ + lg * 8;
        b3src[j] = B3 + (size_t)(n0 + r) * D_ + lg * 8;
    }
    unsigned short *ldA[4], *ldB1[2], *ldB3[2];
#pragma unroll
    for (int j = 0; j < 4; j++) ldA[j] = As + (j * 32 + wave * 8) * 64;
#pragma unroll
    for (int j = 0; j < 2; j++) {
        ldB1[j] = Bs1 + (j * 32 + wave * 8) * 64;
        ldB3[j] = Bs3 + (j * 32 + wave * 8) * 64;
    }

    floatx4 acc1[4][2] = {}; floatx4 acc3[4][2] = {};
    int sx = (l15 & 7);   // fragment-read swizzle key

    for (int k0 = 0; k0 < D_; k0 += 64) {
        __syncthreads();
#pragma unroll
        for (int j = 0; j < 4; j++) GLOAD_LDS16(asrc[j] + k0, ldA[j]);
#pragma unroll
        for (int j = 0; j < 2; j++) {
            GLOAD_LDS16(b1src[j] + k0, ldB1[j]);
            GLOAD_LDS16(b3src[j] + k0, ldB3[j]);
        }
        __syncthreads();

#pragma unroll
        for (int kk = 0; kk < 2; kk++) {
            int pq = ((kk * 4 + quad) ^ sx) * 8;
            bf16x8 af[4], b1f[2], b3f[2];
#pragma unroll
            for (int mi = 0; mi < 4; mi++)
                af[mi] = *(const bf16x8*)(As + (wm + mi * 16 + l15) * 64 + pq);
#pragma unroll
            for (int ni = 0; ni < 2; ni++) {
                b1f[ni] = *(const bf16x8*)(Bs1 + (wn + ni * 16 + l15) * 64 + pq);
                b3f[ni] = *(const bf16x8*)(Bs3 + (wn + ni * 16 + l15) * 64 + pq);
            }
#pragma unroll
            for (int mi = 0; mi < 4; mi++)
#pragma unroll
                for (int ni = 0; ni < 2; ni++) {
                    acc1[mi][ni] = __builtin_amdgcn_mfma_f32_16x16x32_bf16(
                        af[mi], b1f[ni], acc1[mi][ni], 0, 0, 0);
                    acc3[mi][ni] = __builtin_amdgcn_mfma_f32_16x16x32_bf16(
                        af[mi], b3f[ni], acc3[mi][ni], 0, 0, 0);
                }
        }
    }

#pragma unroll
    for (int mi = 0; mi < 4; mi++)
#pragma unroll
        for (int ni = 0; ni < 2; ni++) {
            int col = n0 + wn + ni * 16 + l15;
#pragma unroll
            for (int rr = 0; rr < 4; rr++) {
                int row = m0 + wm + mi * 16 + quad * 4 + rr;
                float g = fminf(acc1[mi][ni][rr], 10.f);
                float u = fminf(fmaxf(acc3[mi][ni][rr], -10.f), 10.f);
                float a = g / (1.f + __expf(-g)) * u;
                act[(size_t)row * I_ + col] = f2b(a);
            }
        }
}

// ---------------- GEMM 2: act @ W2, split-K=2, fp32 partials ----------------

__launch_bounds__(256)
__global__ void gemm_out_kernel(const unsigned short* __restrict__ act,
                                const unsigned short* __restrict__ w2sb,
                                const unsigned short* __restrict__ w2b,
                                const int* __restrict__ tiles,
                                float* __restrict__ outp) {
    __shared__ __align__(16) unsigned short As[128 * 64];
    __shared__ __align__(16) unsigned short Bs[64 * 64];

    int mt = blockIdx.y, ks = blockIdx.z;
    int kbase = ks * KS_;
    const unsigned short* B;
    int m0;
    if (mt < NSHT) {
        B = w2sb; m0 = mt * 128;
    } else {
        int e = tiles[(mt - NSHT) * 2];
        if (e < 0) return;
        m0 = NTOK + tiles[(mt - NSHT) * 2 + 1];
        B = w2b + (size_t)e * I_ * D_;
    }
    float* C = outp + (size_t)ks * ROWS * D_;
    int n0 = blockIdx.x * 64;
    int tid = threadIdx.x;
    int lane = tid & 63, wave = tid >> 6;
    int wm = (wave & 1) * 64, wn = (wave >> 1) * 32;
    int l15 = lane & 15, quad = lane >> 4;

    int rl = lane >> 3, ph = lane & 7, lg = ph ^ rl;
    const unsigned short* asrc[4];
#pragma unroll
    for (int j = 0; j < 4; j++)
        asrc[j] = act + (size_t)(m0 + j * 32 + wave * 8 + rl) * I_ + kbase + lg * 8;
    const unsigned short* bsrc[2];
#pragma unroll
    for (int j = 0; j < 2; j++)
        bsrc[j] = B + (size_t)(n0 + j * 32 + wave * 8 + rl) * I_ + kbase + lg * 8;
    unsigned short *ldA[4], *ldB[2];
#pragma unroll
    for (int j = 0; j < 4; j++) ldA[j] = As + (j * 32 + wave * 8) * 64;
#pragma unroll
    for (int j = 0; j < 2; j++) ldB[j] = Bs + (j * 32 + wave * 8) * 64;

    floatx4 acc[4][2] = {};
    int sx = (l15 & 7);

    for (int k0 = 0; k0 < KS_; k0 += 64) {
        __syncthreads();
#pragma unroll
        for (int j = 0; j < 4; j++) GLOAD_LDS16(asrc[j] + k0, ldA[j]);
#pragma unroll
        for (int j = 0; j < 2; j++) GLOAD_LDS16(bsrc[j] + k0, ldB[j]);
        __syncthreads();

#pragma unroll
        for (int kk = 0; kk < 2; kk++) {
            int pq = ((kk * 4 + quad) ^ sx) * 8;
            bf16x8 af[4], bf[2];
#pragma unroll
            for (int mi = 0; mi < 4; mi++)
                af[mi] = *(const bf16x8*)(As + (wm + mi * 16 + l15) * 64 + pq);
#pragma unroll
            for (int ni = 0; ni < 2; ni++)
                bf[ni] = *(const bf16x8*)(Bs + (wn + ni * 16 + l15) * 64 + pq);
#pragma unroll
            for (int mi = 0; mi < 4; mi++)
#pragma unroll
                for (int ni = 0; ni < 2; ni++)
                    acc[mi][ni] = __builtin_amdgcn_mfma_f32_16x16x32_bf16(
                        af[mi], bf[ni], acc[mi][ni], 0, 0, 0);
        }
    }

#pragma unroll
    for (int mi = 0; mi < 4; mi++)
#pragma unroll
        for (int ni = 0; ni < 2; ni++) {
            int col = n0 + wn + ni * 16 + l15;
#pragma unroll
            for (int rr = 0; rr < 4; rr++) {
                int row = m0 + wm + mi * 16 + quad * 4 + rr;
                C[(size_t)row * D_ + col] = acc[mi][ni][rr];
            }
        }
}

// ---------------- combine: sum split-K partials + weighted routed -----------

__global__ void combine_kernel(const float* __restrict__ outp,
                               const int* __restrict__ pos_of,
                               const float* __restrict__ pair_w,
                               float* __restrict__ out) {
    int gid = blockIdx.x * 256 + threadIdx.x;
    int t = gid / (D_ / 4);
    int j = (gid % (D_ / 4)) * 4;
    int p0 = pos_of[2 * t], p1 = pos_of[2 * t + 1];
    float w0 = pair_w[p0], w1 = pair_w[p1];
    float a0 = 0.f, a1 = 0.f, a2 = 0.f, a3 = 0.f;
#pragma unroll
    for (int ks = 0; ks < SPLITK; ks++) {
        const float* P = outp + (size_t)ks * ROWS * D_;
        float4 a = *(const float4*)(P + (size_t)t * D_ + j);
        float4 b = *(const float4*)(P + (size_t)(NTOK + p0) * D_ + j);
        float4 c = *(const float4*)(P + (size_t)(NTOK + p1) * D_ + j);
        a0 += a.x + w0 * b.x + w1 * c.x;
        a1 += a.y + w0 * b.y + w1 * c.y;
        a2 += a.z + w0 * b.z + w1 * c.z;
        a3 += a.w + w0 * b.w + w1 * c.w;
    }
    float4 o; o.x = a0; o.y = a1; o.z = a2; o.w = a3;
    *(float4*)(out + (size_t)t * D_ + j) = o;
}

// ---------------- launch ----------------

extern "C" void kernel_launch(void* const* d_in, const int* in_sizes, int n_in,
                              void* d_out, int out_size, void* d_ws, size_t ws_size,
                              hipStream_t stream) {
    (void)in_sizes; (void)n_in; (void)out_size; (void)ws_size;
    const float* x   = (const float*)d_in[0];
    const float* gw  = (const float*)d_in[2];
    const float* gb  = (const float*)d_in[3];
    const float* w1  = (const float*)d_in[4];
    const float* w2  = (const float*)d_in[5];
    const float* w3  = (const float*)d_in[6];
    const float* w1s = (const float*)d_in[7];
    const float* w2s = (const float*)d_in[8];
    const float* w3s = (const float*)d_in[9];
    float* out = (float*)d_out;

    char* ws = (char*)d_ws;
    size_t off = 0;
    auto alloc = [&](size_t bytes) {
        size_t o = (off + 255) & ~(size_t)255;
        off = o + bytes;
        return (void*)(ws + o);
    };
    unsigned short* xb   = (unsigned short*)alloc((size_t)NTOK * D_ * 2);
    unsigned short* w1b  = (unsigned short*)alloc((size_t)E_ * I_ * D_ * 2);
    unsigned short* w3b  = (unsigned short*)alloc((size_t)E_ * I_ * D_ * 2);
    unsigned short* w2b  = (unsigned short*)alloc((size_t)E_ * I_ * D_ * 2);
    unsigned short* w1sb = (unsigned short*)alloc((size_t)I_ * D_ * 2);
    unsigned short* w3sb = (unsigned short*)alloc((size_t)I_ * D_ * 2);
    unsigned short* w2sb = (unsigned short*)alloc((size_t)I_ * D_ * 2);
    unsigned short* act  = (unsigned short*)alloc((size_t)ROWS * I_ * 2);
    float* outp = (float*)alloc((size_t)SPLITK * ROWS * D_ * 4);
    int*   idx  = (int*)alloc((size_t)NTOK * 2 * 4);
    float* wts  = (float*)alloc((size_t)NTOK * 2 * 4);
    int*   ptok = (int*)alloc((size_t)NPMAX * 4);
    float* pw   = (float*)alloc((size_t)NPMAX * 4);
    int*   posf = (int*)alloc((size_t)NTOK * 2 * 4);
    int*   tls  = (int*)alloc((size_t)MAXTILES * 2 * 4);

    prep_kernel<<<12416, 256, 0, stream>>>(x, gw, gb, w1, w3, w1s, w3s,
                                           xb, w1b, w3b, w1sb, w3sb, idx, wts);
    route_build_kernel<<<1, 256, 0, stream>>>(idx, wts, ptok, pw, posf, tls);
    gemm_act_kernel<<<dim3(I_ / 64, 168), 256, 0, stream>>>(
        xb, w1sb, w3sb, w1b, w3b, tls, ptok, act, w2, w2s, w2b, w2sb);
    gemm_out_kernel<<<dim3(D_ / 64, NSHT + MAXTILES, SPLITK), 256, 0, stream>>>(
        act, w2sb, w2b, tls, outp);
    combine_kernel<<<NTOK * (D_ / 4) / 256, 256, 0, stream>>>(outp, posf, pw, out);
}

// Round 3
// 436.916 us; speedup vs baseline: 1.0659x; 1.0571x over previous
//
#include <hip/hip_runtime.h>

// DeepSeek MoE (N=2048, D=768, I=3072, E=8, K=2 + shared expert), fp32 in/out,
// bf16 MFMA compute. R6: pipeline-overlap restructure. The serial prep pass is
// reduced to cast_x+gating+shared-weight transposes (~45 MB); the big w1/w3
// routed-weight transposes (151 MB rd + 75 MB wr) are folded into the
// shared-expert GEMM1 launch (which needs neither routing nor w1b/w3b), and
// route_build rides along as one extra block. The w2 transposes stay folded
// into the routed GEMM1 (R5 trick). Dependencies all resolve at kernel
// boundaries: K3 reads w1b/w3b/tiles (K2), gemm_out reads w2b (K3).

#define D_ 768
#define I_ 3072
#define E_ 8
#define NTOK 2048
#define NPMAX 5120          // 4096 pairs + worst-case 128-padding per expert
#define MAXTILES 40
#define NSHT 16             // shared-expert M tiles: 2048/128
#define ROWS (NTOK + NPMAX) // unified act/out rows
#define SPLITK 2
#define KS_ (I_ / SPLITK)   // 1536

typedef __bf16 bf16x8 __attribute__((ext_vector_type(8)));
typedef float floatx4 __attribute__((ext_vector_type(4)));

#define GLOAD_LDS16(g, l) __builtin_amdgcn_global_load_lds( \
    (const __attribute__((address_space(1))) void*)(g),     \
    (__attribute__((address_space(3))) void*)(l), 16, 0, 0)

__device__ __forceinline__ unsigned short f2b(float f) {
    unsigned int u = __float_as_uint(f);
    u += 0x7fffu + ((u >> 16) & 1u);          // RNE to bf16
    return (unsigned short)(u >> 16);
}

// 64x64 fp32->bf16 transpose tile through LDS scratch (runtime R,C).
__device__ __forceinline__ void transpose_tile(const float* __restrict__ s,
                                               unsigned short* __restrict__ d,
                                               int R, int C, int r0, int c0,
                                               float (*t)[65], int tid) {
#pragma unroll
    for (int j = 0; j < 4; j++) {
        int slot = tid + j * 256;
        int rr = slot >> 4, c4 = (slot & 15) * 4;
        float4 v = *(const float4*)(s + (size_t)(r0 + rr) * C + c0 + c4);
        t[rr][c4] = v.x; t[rr][c4 + 1] = v.y; t[rr][c4 + 2] = v.z; t[rr][c4 + 3] = v.w;
    }
    __syncthreads();
#pragma unroll
    for (int j = 0; j < 2; j++) {
        int slot = tid + j * 256;
        int c = slot >> 3, rs = (slot & 7) * 8;
        unsigned short o[8] __attribute__((aligned(16)));
#pragma unroll
        for (int i = 0; i < 8; i++) o[i] = f2b(t[rs + i][c]);
        *(int4*)(d + (size_t)(c0 + c) * R + r0 + rs) = *(const int4*)o;
    }
}

// ---------------- K1: cast_x + gating + shared-weight transposes ------------

__global__ __launch_bounds__(256) void prep_lite_kernel(
    const float* __restrict__ x, const float* __restrict__ gw,
    const float* __restrict__ gbias,
    const float* __restrict__ w1s, const float* __restrict__ w3s,
    const float* __restrict__ w2s,
    unsigned short* __restrict__ xb,
    unsigned short* __restrict__ w1sb, unsigned short* __restrict__ w3sb,
    unsigned short* __restrict__ w2sb,
    int* __restrict__ idx, float* __restrict__ wts) {
    __shared__ float t[64][65];
    int b = blockIdx.x, tid = threadIdx.x;
    if (b < 1728) {
        int z = b / 576, r = b % 576;
        if (z < 2) {            // w1s/w3s: [D][I]
            int bx = r % 48, by = r / 48;
            transpose_tile(z ? w3s : w1s, z ? w3sb : w1sb, D_, I_,
                           by * 64, bx * 64, t, tid);
        } else {                // w2s: [I][D]
            int tx = r % 12, ty = r / 12;
            transpose_tile(w2s, w2sb, I_, D_, ty * 64, tx * 64, t, tid);
        }
    } else if (b < 3264) {
        int gid = (b - 1728) * 256 + tid;
        float4 v = *(const float4*)(x + (size_t)gid * 4);
        ushort4 o;
        o.x = f2b(v.x); o.y = f2b(v.y); o.z = f2b(v.z); o.w = f2b(v.w);
        *(ushort4*)(xb + (size_t)gid * 4) = o;
    } else {
        int tok = (b - 3264) * 4 + (tid >> 6);
        int lane = tid & 63;
        float z[E_];
#pragma unroll
        for (int e = 0; e < E_; e++) z[e] = 0.f;
        const float* xr = x + (size_t)tok * D_;
        for (int j = lane; j < D_; j += 64) {
            float xv = xr[j];
            const float* g = gw + (size_t)j * E_;
#pragma unroll
            for (int e = 0; e < E_; e++) z[e] += xv * g[e];
        }
#pragma unroll
        for (int off = 32; off > 0; off >>= 1)
#pragma unroll
            for (int e = 0; e < E_; e++) z[e] += __shfl_down(z[e], off, 64);
        if (lane == 0) {
            float s[E_], r[E_];
#pragma unroll
            for (int e = 0; e < E_; e++) {
                float zz = z[e];
                float sp = zz > 0.f ? zz + log1pf(expf(-zz)) : log1pf(expf(zz));
                s[e] = sqrtf(sp);
                r[e] = s[e] + gbias[e];
            }
            int i0 = 0;
            for (int e = 1; e < E_; e++) if (r[e] > r[i0]) i0 = e;
            int i1 = (i0 == 0) ? 1 : 0;
            for (int e = 0; e < E_; e++) if (e != i0 && r[e] > r[i1]) i1 = e;
            float w0 = s[i0], w1v = s[i1];
            float inv = 1.f / fmaxf(w0 + w1v, 1e-6f);
            idx[2 * tok] = i0; idx[2 * tok + 1] = i1;
            wts[2 * tok] = w0 * inv; wts[2 * tok + 1] = w1v * inv;
        }
    }
}

// ---------------- K2: shared GEMM1 + w1/w3 transposes + route_build ---------
// grid (48, 209). byi==0: route_build at bxi==0 (rest idle).
// t = byi-1: t%13==0 -> shared GEMM row (mt = t/13, 16 rows);
// else transpose slot (192 rows x 48 = 9216 = 2*8*576 w1/w3 tiles).

__launch_bounds__(256)
__global__ void gemm_shared_kernel(const unsigned short* __restrict__ xb,
                                   const unsigned short* __restrict__ w1sb,
                                   const unsigned short* __restrict__ w3sb,
                                   unsigned short* __restrict__ act,
                                   const float* __restrict__ w1,
                                   const float* __restrict__ w3,
                                   unsigned short* __restrict__ w1b,
                                   unsigned short* __restrict__ w3b,
                                   const int* __restrict__ idx,
                                   const float* __restrict__ wts,
                                   int* __restrict__ pair_token,
                                   float* __restrict__ pair_w,
                                   int* __restrict__ pos_of,
                                   int* __restrict__ tiles) {
    __shared__ __align__(16) unsigned short smem[128 * 64 + 64 * 64 + 64 * 64]; // 32 KB
    unsigned short* As  = smem;
    unsigned short* Bs1 = smem + 128 * 64;
    unsigned short* Bs3 = smem + 128 * 64 + 64 * 64;

    int bxi = blockIdx.x, byi = blockIdx.y, tid = threadIdx.x;

    if (byi == 0) {
        if (bxi) return;
        // ---- route build (single block) ----
        int* cnt = (int*)smem; int* seg = cnt + E_; int* cur = cnt + 2 * E_;
        if (tid < E_) { cnt[tid] = 0; cur[tid] = 0; }
        __syncthreads();
        for (int p = tid; p < NTOK * 2; p += 256) atomicAdd(&cnt[idx[p]], 1);
        __syncthreads();
        if (tid == 0) {
            int off = 0, nt = 0;
            for (int e = 0; e < E_; e++) {
                seg[e] = off;
                int te = (cnt[e] + 127) >> 7;
                for (int j = 0; j < te; j++) {
                    tiles[nt * 2] = e; tiles[nt * 2 + 1] = off + j * 128; nt++;
                }
                off += te * 128;
            }
            for (; nt < MAXTILES; nt++) { tiles[nt * 2] = -1; tiles[nt * 2 + 1] = 0; }
        }
        for (int p = tid; p < NPMAX; p += 256) pair_token[p] = -1;
        __syncthreads();
        for (int p = tid; p < NTOK * 2; p += 256) {
            int e = idx[p];
            int r = atomicAdd(&cur[e], 1);
            int pos = seg[e] + r;
            pair_token[pos] = p >> 1;
            pair_w[pos] = wts[p];
            pos_of[p] = pos;
        }
        return;
    }

    int t = byi - 1;
    if (t % 13) {
        // ---- w1/w3 transpose tile ----
        int slot = t - t / 13 - 1;             // 0..191
        int b2 = slot * 48 + bxi;              // 0..9215
        int z = b2 / 576, r = b2 % 576;
        int bx = r % 48, by = r / 48;
        const float* s; unsigned short* d;
        if (z < 8) { s = w1 + (size_t)z * D_ * I_;       d = w1b + (size_t)z * D_ * I_; }
        else       { s = w3 + (size_t)(z - 8) * D_ * I_; d = w3b + (size_t)(z - 8) * D_ * I_; }
        transpose_tile(s, d, D_, I_, by * 64, bx * 64, (float(*)[65])smem, tid);
        return;
    }

    // ---- shared-expert GEMM row ----
    int mt = t / 13;                           // 0..15
    int m0 = mt * 128;
    int n0 = bxi * 64;
    int lane = tid & 63, wave = tid >> 6;
    int wm = (wave & 1) * 64, wn = (wave >> 1) * 32;
    int l15 = lane & 15, quad = lane >> 4;

    int rl = lane >> 3, ph = lane & 7, lg = ph ^ rl;
    const unsigned short* asrc[4];
#pragma unroll
    for (int j = 0; j < 4; j++)
        asrc[j] = xb + (size_t)(m0 + j * 32 + wave * 8 + rl) * D_ + lg * 8;
    const unsigned short *b1src[2], *b3src[2];
#pragma unroll
    for (int j = 0; j < 2; j++) {
        int r = j * 32 + wave * 8 + rl;
        b1src[j] = w1sb + (size_t)(n0 + r) * D_ + lg * 8;
        b3src[j] = w3sb + (size_t)(n0 + r) * D_ + lg * 8;
    }
    unsigned short *ldA[4], *ldB1[2], *ldB3[2];
#pragma unroll
    for (int j = 0; j < 4; j++) ldA[j] = As + (j * 32 + wave * 8) * 64;
#pragma unroll
    for (int j = 0; j < 2; j++) {
        ldB1[j] = Bs1 + (j * 32 + wave * 8) * 64;
        ldB3[j] = Bs3 + (j * 32 + wave * 8) * 64;
    }

    floatx4 acc1[4][2] = {}; floatx4 acc3[4][2] = {};
    int sx = (l15 & 7);

    for (int k0 = 0; k0 < D_; k0 += 64) {
        __syncthreads();
#pragma unroll
        for (int j = 0; j < 4; j++) GLOAD_LDS16(asrc[j] + k0, ldA[j]);
#pragma unroll
        for (int j = 0; j < 2; j++) {
            GLOAD_LDS16(b1src[j] + k0, ldB1[j]);
            GLOAD_LDS16(b3src[j] + k0, ldB3[j]);
        }
        __syncthreads();

#pragma unroll
        for (int kk = 0; kk < 2; kk++) {
            int pq = ((kk * 4 + quad) ^ sx) * 8;
            bf16x8 af[4], b1f[2], b3f[2];
#pragma unroll
            for (int mi = 0; mi < 4; mi++)
                af[mi] = *(const bf16x8*)(As + (wm + mi * 16 + l15) * 64 + pq);
#pragma unroll
            for (int ni = 0; ni < 2; ni++) {
                b1f[ni] = *(const bf16x8*)(Bs1 + (wn + ni * 16 + l15) * 64 + pq);
                b3f[ni] = *(const bf16x8*)(Bs3 + (wn + ni * 16 + l15) * 64 + pq);
            }
#pragma unroll
            for (int mi = 0; mi < 4; mi++)
#pragma unroll
                for (int ni = 0; ni < 2; ni++) {
                    acc1[mi][ni] = __builtin_amdgcn_mfma_f32_16x16x32_bf16(
                        af[mi], b1f[ni], acc1[mi][ni], 0, 0, 0);
                    acc3[mi][ni] = __builtin_amdgcn_mfma_f32_16x16x32_bf16(
                        af[mi], b3f[ni], acc3[mi][ni], 0, 0, 0);
                }
        }
    }

#pragma unroll
    for (int mi = 0; mi < 4; mi++)
#pragma unroll
        for (int ni = 0; ni < 2; ni++) {
            int col = n0 + wn + ni * 16 + l15;
#pragma unroll
            for (int rr = 0; rr < 4; rr++) {
                int row = m0 + wm + mi * 16 + quad * 4 + rr;
                float g = fminf(acc1[mi][ni][rr], 10.f);
                float u = fminf(fmaxf(acc3[mi][ni][rr], -10.f), 10.f);
                float a = g / (1.f + __expf(-g)) * u;
                act[(size_t)row * I_ + col] = f2b(a);
            }
        }
}

// ---------------- K3: routed GEMM1 (gather) + w2 transposes -----------------
// grid (48, 136). g=byi/17, h=byi%17: h<5 -> GEMM tile mt=g*5+h (40 rows);
// else transpose slot g*12+(h-5) (96 rows x 48 = 4608 = 8*576 w2 tiles).

__launch_bounds__(256)
__global__ void gemm_routed_kernel(const unsigned short* __restrict__ xb,
                                   const unsigned short* __restrict__ w1b,
                                   const unsigned short* __restrict__ w3b,
                                   const int* __restrict__ tiles,
                                   const int* __restrict__ pair_token,
                                   unsigned short* __restrict__ act,
                                   const float* __restrict__ w2,
                                   unsigned short* __restrict__ w2b) {
    __shared__ __align__(16) unsigned short smem[128 * 64 + 64 * 64 + 64 * 64]; // 32 KB
    unsigned short* As  = smem;
    unsigned short* Bs1 = smem + 128 * 64;
    unsigned short* Bs3 = smem + 128 * 64 + 64 * 64;

    int bxi = blockIdx.x, byi = blockIdx.y, tid = threadIdx.x;
    int g = byi / 17, h = byi % 17;

    if (h >= 5) {
        // ---- w2 transpose tile ----
        int slot = g * 12 + (h - 5);           // 0..95
        int b2 = slot * 48 + bxi;              // 0..4607
        int z = b2 / 576, r = b2 % 576;
        int tx = r % 12, ty = r / 12;
        transpose_tile(w2 + (size_t)z * I_ * D_, w2b + (size_t)z * I_ * D_,
                       I_, D_, ty * 64, tx * 64, (float(*)[65])smem, tid);
        return;
    }

    int mt = g * 5 + h;                        // 0..39
    int e = tiles[mt * 2];
    if (e < 0) return;
    int m0 = NTOK + tiles[mt * 2 + 1];
    const unsigned short* B1 = w1b + (size_t)e * I_ * D_;
    const unsigned short* B3 = w3b + (size_t)e * I_ * D_;

    int n0 = bxi * 64;
    int lane = tid & 63, wave = tid >> 6;
    int wm = (wave & 1) * 64, wn = (wave >> 1) * 32;
    int l15 = lane & 15, quad = lane >> 4;

    int rl = lane >> 3, ph = lane & 7, lg = ph ^ rl;
    const unsigned short* asrc[4];
#pragma unroll
    for (int j = 0; j < 4; j++) {
        int r = j * 32 + wave * 8 + rl;
        int tok = pair_token[m0 - NTOK + r]; if (tok < 0) tok = 0;
        asrc[j] = xb + (size_t)tok * D_ + lg * 8;
    }
    const unsigned short *b1src[2], *b3src[2];
#pragma unroll
    for (int j = 0; j < 2; j++) {
        int r = j * 32 + wave * 8 + rl;
        b1src[j] = B1 + (size_t)(n0 + r) * D_ + lg * 8;
        b3src[j] = B3 + (size_t)(n0 + r) * D_ + lg * 8;
    }
    unsigned short *ldA[4], *ldB1[2], *ldB3[2];
#pragma unroll
    for (int j = 0; j < 4; j++) ldA[j] = As + (j * 32 + wave * 8) * 64;
#pragma unroll
    for (int j = 0; j < 2; j++) {
        ldB1[j] = Bs1 + (j * 32 + wave * 8) * 64;
        ldB3[j] = Bs3 + (j * 32 + wave * 8) * 64;
    }

    floatx4 acc1[4][2] = {}; floatx4 acc3[4][2] = {};
    int sx = (l15 & 7);

    for (int k0 = 0; k0 < D_; k0 += 64) {
        __syncthreads();
#pragma unroll
        for (int j = 0; j < 4; j++) GLOAD_LDS16(asrc[j] + k0, ldA[j]);
#pragma unroll
        for (int j = 0; j < 2; j++) {
            GLOAD_LDS16(b1src[j] + k0, ldB1[j]);
            GLOAD_LDS16(b3src[j] + k0, ldB3[j]);
        }
        __syncthreads();

#pragma unroll
        for (int kk = 0; kk < 2; kk++) {
            int pq = ((kk * 4 + quad) ^ sx) * 8;
            bf16x8 af[4], b1f[2], b3f[2];
#pragma unroll
            for (int mi = 0; mi < 4; mi++)
                af[mi] = *(const bf16x8*)(As + (wm + mi * 16 + l15) * 64 + pq);
#pragma unroll
            for (int ni = 0; ni < 2; ni++) {
                b1f[ni] = *(const bf16x8*)(Bs1 + (wn + ni * 16 + l15) * 64 + pq);
                b3f[ni] = *(const bf16x8*)(Bs3 + (wn + ni * 16 + l15) * 64 + pq);
            }
#pragma unroll
            for (int mi = 0; mi < 4; mi++)
#pragma unroll
                for (int ni = 0; ni < 2; ni++) {
                    acc1[mi][ni] = __builtin_amdgcn_mfma_f32_16x16x32_bf16(
                        af[mi], b1f[ni], acc1[mi][ni], 0, 0, 0);
                    acc3[mi][ni] = __builtin_amdgcn_mfma_f32_16x16x32_bf16(
                        af[mi], b3f[ni], acc3[mi][ni], 0, 0, 0);
                }
        }
    }

#pragma unroll
    for (int mi = 0; mi < 4; mi++)
#pragma unroll
        for (int ni = 0; ni < 2; ni++) {
            int col = n0 + wn + ni * 16 + l15;
#pragma unroll
            for (int rr = 0; rr < 4; rr++) {
                int row = m0 + wm + mi * 16 + quad * 4 + rr;
                float g = fminf(acc1[mi][ni][rr], 10.f);
                float u = fminf(fmaxf(acc3[mi][ni][rr], -10.f), 10.f);
                float a = g / (1.f + __expf(-g)) * u;
                act[(size_t)row * I_ + col] = f2b(a);
            }
        }
}

// ---------------- GEMM 2: act @ W2, split-K=2, fp32 partials ----------------

__launch_bounds__(256)
__global__ void gemm_out_kernel(const unsigned short* __restrict__ act,
                                const unsigned short* __restrict__ w2sb,
                                const unsigned short* __restrict__ w2b,
                                const int* __restrict__ tiles,
                                float* __restrict__ outp) {
    __shared__ __align__(16) unsigned short As[128 * 64];
    __shared__ __align__(16) unsigned short Bs[64 * 64];

    int mt = blockIdx.y, ks = blockIdx.z;
    int kbase = ks * KS_;
    const unsigned short* B;
    int m0;
    if (mt < NSHT) {
        B = w2sb; m0 = mt * 128;
    } else {
        int e = tiles[(mt - NSHT) * 2];
        if (e < 0) return;
        m0 = NTOK + tiles[(mt - NSHT) * 2 + 1];
        B = w2b + (size_t)e * I_ * D_;
    }
    float* C = outp + (size_t)ks * ROWS * D_;
    int n0 = blockIdx.x * 64;
    int tid = threadIdx.x;
    int lane = tid & 63, wave = tid >> 6;
    int wm = (wave & 1) * 64, wn = (wave >> 1) * 32;
    int l15 = lane & 15, quad = lane >> 4;

    int rl = lane >> 3, ph = lane & 7, lg = ph ^ rl;
    const unsigned short* asrc[4];
#pragma unroll
    for (int j = 0; j < 4; j++)
        asrc[j] = act + (size_t)(m0 + j * 32 + wave * 8 + rl) * I_ + kbase + lg * 8;
    const unsigned short* bsrc[2];
#pragma unroll
    for (int j = 0; j < 2; j++)
        bsrc[j] = B + (size_t)(n0 + j * 32 + wave * 8 + rl) * I_ + kbase + lg * 8;
    unsigned short *ldA[4], *ldB[2];
#pragma unroll
    for (int j = 0; j < 4; j++) ldA[j] = As + (j * 32 + wave * 8) * 64;
#pragma unroll
    for (int j = 0; j < 2; j++) ldB[j] = Bs + (j * 32 + wave * 8) * 64;

    floatx4 acc[4][2] = {};
    int sx = (l15 & 7);

    for (int k0 = 0; k0 < KS_; k0 += 64) {
        __syncthreads();
#pragma unroll
        for (int j = 0; j < 4; j++) GLOAD_LDS16(asrc[j] + k0, ldA[j]);
#pragma unroll
        for (int j = 0; j < 2; j++) GLOAD_LDS16(bsrc[j] + k0, ldB[j]);
        __syncthreads();

#pragma unroll
        for (int kk = 0; kk < 2; kk++) {
            int pq = ((kk * 4 + quad) ^ sx) * 8;
            bf16x8 af[4], bf[2];
#pragma unroll
            for (int mi = 0; mi < 4; mi++)
                af[mi] = *(const bf16x8*)(As + (wm + mi * 16 + l15) * 64 + pq);
#pragma unroll
            for (int ni = 0; ni < 2; ni++)
                bf[ni] = *(const bf16x8*)(Bs + (wn + ni * 16 + l15) * 64 + pq);
#pragma unroll
            for (int mi = 0; mi < 4; mi++)
#pragma unroll
                for (int ni = 0; ni < 2; ni++)
                    acc[mi][ni] = __builtin_amdgcn_mfma_f32_16x16x32_bf16(
                        af[mi], bf[ni], acc[mi][ni], 0, 0, 0);
        }
    }

#pragma unroll
    for (int mi = 0; mi < 4; mi++)
#pragma unroll
        for (int ni = 0; ni < 2; ni++) {
            int col = n0 + wn + ni * 16 + l15;
#pragma unroll
            for (int rr = 0; rr < 4; rr++) {
                int row = m0 + wm + mi * 16 + quad * 4 + rr;
                C[(size_t)row * D_ + col] = acc[mi][ni][rr];
            }
        }
}

// ---------------- combine: sum split-K partials + weighted routed -----------

__global__ void combine_kernel(const float* __restrict__ outp,
                               const int* __restrict__ pos_of,
                               const float* __restrict__ pair_w,
                               float* __restrict__ out) {
    int gid = blockIdx.x * 256 + threadIdx.x;
    int t = gid / (D_ / 4);
    int j = (gid % (D_ / 4)) * 4;
    int p0 = pos_of[2 * t], p1 = pos_of[2 * t + 1];
    float w0 = pair_w[p0], w1 = pair_w[p1];
    float a0 = 0.f, a1 = 0.f, a2 = 0.f, a3 = 0.f;
#pragma unroll
    for (int ks = 0; ks < SPLITK; ks++) {
        const float* P = outp + (size_t)ks * ROWS * D_;
        float4 a = *(const float4*)(P + (size_t)t * D_ + j);
        float4 b = *(const float4*)(P + (size_t)(NTOK + p0) * D_ + j);
        float4 c = *(const float4*)(P + (size_t)(NTOK + p1) * D_ + j);
        a0 += a.x + w0 * b.x + w1 * c.x;
        a1 += a.y + w0 * b.y + w1 * c.y;
        a2 += a.z + w0 * b.z + w1 * c.z;
        a3 += a.w + w0 * b.w + w1 * c.w;
    }
    float4 o; o.x = a0; o.y = a1; o.z = a2; o.w = a3;
    *(float4*)(out + (size_t)t * D_ + j) = o;
}

// ---------------- launch ----------------

extern "C" void kernel_launch(void* const* d_in, const int* in_sizes, int n_in,
                              void* d_out, int out_size, void* d_ws, size_t ws_size,
                              hipStream_t stream) {
    (void)in_sizes; (void)n_in; (void)out_size; (void)ws_size;
    const float* x   = (const float*)d_in[0];
    const float* gw  = (const float*)d_in[2];
    const float* gb  = (const float*)d_in[3];
    const float* w1  = (const float*)d_in[4];
    const float* w2  = (const float*)d_in[5];
    const float* w3  = (const float*)d_in[6];
    const float* w1s = (const float*)d_in[7];
    const float* w2s = (const float*)d_in[8];
    const float* w3s = (const float*)d_in[9];
    float* out = (float*)d_out;

    char* ws = (char*)d_ws;
    size_t off = 0;
    auto alloc = [&](size_t bytes) {
        size_t o = (off + 255) & ~(size_t)255;
        off = o + bytes;
        return (void*)(ws + o);
    };
    unsigned short* xb   = (unsigned short*)alloc((size_t)NTOK * D_ * 2);
    unsigned short* w1b  = (unsigned short*)alloc((size_t)E_ * I_ * D_ * 2);
    unsigned short* w3b  = (unsigned short*)alloc((size_t)E_ * I_ * D_ * 2);
    unsigned short* w2b  = (unsigned short*)alloc((size_t)E_ * I_ * D_ * 2);
    unsigned short* w1sb = (unsigned short*)alloc((size_t)I_ * D_ * 2);
    unsigned short* w3sb = (unsigned short*)alloc((size_t)I_ * D_ * 2);
    unsigned short* w2sb = (unsigned short*)alloc((size_t)I_ * D_ * 2);
    unsigned short* act  = (unsigned short*)alloc((size_t)ROWS * I_ * 2);
    float* outp = (float*)alloc((size_t)SPLITK * ROWS * D_ * 4);
    int*   idx  = (int*)alloc((size_t)NTOK * 2 * 4);
    float* wts  = (float*)alloc((size_t)NTOK * 2 * 4);
    int*   ptok = (int*)alloc((size_t)NPMAX * 4);
    float* pw   = (float*)alloc((size_t)NPMAX * 4);
    int*   posf = (int*)alloc((size_t)NTOK * 2 * 4);
    int*   tls  = (int*)alloc((size_t)MAXTILES * 2 * 4);

    prep_lite_kernel<<<3776, 256, 0, stream>>>(x, gw, gb, w1s, w3s, w2s,
                                               xb, w1sb, w3sb, w2sb, idx, wts);
    gemm_shared_kernel<<<dim3(48, 209), 256, 0, stream>>>(
        xb, w1sb, w3sb, act, w1, w3, w1b, w3b, idx, wts, ptok, pw, posf, tls);
    gemm_routed_kernel<<<dim3(48, 136), 256, 0, stream>>>(
        xb, w1b, w3b, tls, ptok, act, w2, w2b);
    gemm_out_kernel<<<dim3(D_ / 64, NSHT + MAXTILES, SPLITK), 256, 0, stream>>>(
        act, w2sb, w2b, tls, outp);
    combine_kernel<<<NTOK * (D_ / 4) / 256, 256, 0, stream>>>(outp, posf, pw, out);
}